// Round 8
// baseline (450.546 us; speedup 1.0000x reference)
//
#include <hip/hip_runtime.h>
#include <stdint.h>

typedef _Float16 f16;
typedef _Float16 f16x8 __attribute__((ext_vector_type(8)));
typedef _Float16 f16x4 __attribute__((ext_vector_type(4)));
typedef float f32x4 __attribute__((ext_vector_type(4)));

__device__ __forceinline__ void gload_lds16(const void* g, void* l) {
    __builtin_amdgcn_global_load_lds(
        (const __attribute__((address_space(1))) unsigned int*)g,
        (__attribute__((address_space(3))) unsigned int*)l, 16, 0, 0);
}

#define VMWAIT8() asm volatile("s_waitcnt vmcnt(8)" ::: "memory")
#define VMWAIT0() asm volatile("s_waitcnt vmcnt(0)" ::: "memory")
#define LGKM0()   asm volatile("s_waitcnt lgkmcnt(0)" ::: "memory")

// ---------------------------------------------------------------------------
struct Cvt4 {
    const float* s[4];
    f16* d[4];
    int n8[4];
};
__global__ __launch_bounds__(256) void cvt_plain4(Cvt4 c) {
    const int seg = blockIdx.y;
    const int i = blockIdx.x * 256 + threadIdx.x;
    if (i >= c.n8[seg]) return;
    const float4* s4 = (const float4*)c.s[seg];
    float4 a = s4[2 * (size_t)i];
    float4 b = s4[2 * (size_t)i + 1];
    f16x8 o;
    o[0] = (f16)a.x; o[1] = (f16)a.y; o[2] = (f16)a.z; o[3] = (f16)a.w;
    o[4] = (f16)b.x; o[5] = (f16)b.y; o[6] = (f16)b.z; o[7] = (f16)b.w;
    *(f16x8*)(c.d[seg] + (size_t)i * 8) = o;
}

// ---------------------------------------------------------------------------
struct T3 { const float* s[3]; f16* d[3]; };
__global__ __launch_bounds__(256) void cvt_transpose3(T3 c) {
    const int bid = blockIdx.x;
    const int dt = bid & 15;
    const int et = (bid >> 4) & 15;
    const int zz = bid >> 8;
    const int m = zz >> 3, h = zz & 7;
    const float* src = c.s[m] + (size_t)h * 1048576;
    f16* dst = c.d[m] + (size_t)h * 1048576;
    __shared__ f16 t[64][72];
    const int r  = threadIdx.x >> 2;
    const int cq = threadIdx.x & 3;
    const int d0 = dt * 64, e0 = et * 64;
#pragma unroll
    for (int i = 0; i < 4; ++i) {
        const int cc = cq * 4 + i * 16;
        float4 vv = *(const float4*)(src + (size_t)(d0 + r) * 1024 + e0 + cc);
        t[cc + 0][r] = (f16)vv.x;
        t[cc + 1][r] = (f16)vv.y;
        t[cc + 2][r] = (f16)vv.z;
        t[cc + 3][r] = (f16)vv.w;
    }
    __syncthreads();
#pragma unroll
    for (int i = 0; i < 4; ++i) {
        const int cc = cq * 4 + i * 16;
        f16x4 w;
        w[0] = t[r][cc + 0];
        w[1] = t[r][cc + 1];
        w[2] = t[r][cc + 2];
        w[3] = t[r][cc + 3];
        *(f16x4*)(dst + (size_t)(e0 + r) * 1024 + d0 + cc) = w;
    }
}

// ---------------------------------------------------------------------------
// R1-verified 128x128 BT-GEMM (small/odd-grid shapes + split-K final).
template <typename OutT>
__global__ __launch_bounds__(256, 2) void gemm_bt(
    const f16* __restrict__ A, const f16* __restrict__ B, OutT* __restrict__ C,
    int ldA, int ldB, long long ldC, int K, float alpha,
    long long sAh, long long sAb, long long sBh, long long sBb,
    long long sCh, long long sCb, int NB) {
    const int z = blockIdx.z;
    const int h = z / NB, bb = z % NB;
    A += h * sAh + bb * sAb;
    B += h * sBh + bb * sBb;
    C += h * sCh + bb * sCb;

    const int row0 = blockIdx.y * 128;
    const int col0 = blockIdx.x * 128;

    __shared__ __align__(16) f16 smA[128 * 64];
    __shared__ __align__(16) f16 smB[128 * 64];

    const int tid  = threadIdx.x;
    const int lane = tid & 63;
    const int wid  = tid >> 6;
    const int wr   = (wid >> 1) * 64;
    const int wc   = (wid & 1) * 64;
    const int fr   = lane & 15;
    const int fkb  = (lane >> 4) * 16;

    f32x4 acc[4][4] = {};

    const int nkt = K >> 6;
    for (int kt = 0; kt < nkt; ++kt) {
#pragma unroll
        for (int it = 0; it < 4; ++it) {
            int p = (it * 256 + tid) * 16;
            int n = p ^ (((p >> 7) & 7) << 4);
            int r   = n >> 7;
            int kel = (n & 127) >> 1;
            size_t ga = (size_t)(row0 + r) * (size_t)ldA + (size_t)(kt * 64 + kel);
            gload_lds16(A + ga, (char*)smA + p);
            size_t gb = (size_t)(col0 + r) * (size_t)ldB + (size_t)(kt * 64 + kel);
            gload_lds16(B + gb, (char*)smB + p);
        }
        __syncthreads();

#pragma unroll
        for (int ks = 0; ks < 2; ++ks) {
            f16x8 af[4], bf[4];
#pragma unroll
            for (int i = 0; i < 4; ++i) {
                int rowA = wr + i * 16 + fr;
                int na   = rowA * 128 + ks * 64 + fkb;
                af[i] = *(const f16x8*)((const char*)smA + (na ^ ((rowA & 7) << 4)));
                int rowB = wc + i * 16 + fr;
                int nb   = rowB * 128 + ks * 64 + fkb;
                bf[i] = *(const f16x8*)((const char*)smB + (nb ^ ((rowB & 7) << 4)));
            }
#pragma unroll
            for (int i = 0; i < 4; ++i)
#pragma unroll
                for (int j = 0; j < 4; ++j)
                    acc[i][j] = __builtin_amdgcn_mfma_f32_16x16x32_f16(
                        af[i], bf[j], acc[i][j], 0, 0, 0);
        }
        __syncthreads();
    }

    const int er = (lane >> 4) * 4;
#pragma unroll
    for (int i = 0; i < 4; ++i)
#pragma unroll
        for (int j = 0; j < 4; ++j)
#pragma unroll
            for (int r = 0; r < 4; ++r) {
                size_t idx = (size_t)(row0 + wr + i * 16 + er + r) * (size_t)ldC +
                             (size_t)(col0 + wc + j * 16 + fr);
                C[idx] = (OutT)(acc[i][j][r] * alpha);
            }
}

// ---------------------------------------------------------------------------
// 256x256 BT-GEMM, 8-phase counted-vmcnt schedule (T3+T4), BK=64 as 2 k-halves.
// LDS per buffer: [A: 2(kh) x 256 x 64B][B: same] = 64 KB; 2 buffers = 128 KB.
// Per tile t (buf p=t&1): ph1{stage (t+1)Ak1->p^1; read A0-3k0+Bk0; 16 MFMA}
//   ph2{stage (t+1)Bk1; read A4-7k0; 16 MFMA}; vmcnt(8) [own k1 landed]
//   ph3{stage (t+2)Ak0->p k0 (freed); read A0-3k1+Bk1; 16 MFMA}
//   ph4{stage (t+2)Bk0; read A4-7k1; 16 MFMA}; vmcnt(8|0 last); barrier.
// Waits derived: 2 loads/half, <=6 halves outstanding; vmcnt(8) retires the
// oldest 2 halves, exactly the ones the next 2 phases consume.
template <typename OutT>
__global__ __launch_bounds__(512, 2) void gemm8p(
    const f16* __restrict__ A, const f16* __restrict__ B, OutT* __restrict__ C,
    int ldA, int ldB, long long ldC, int K, float alpha,
    long long sAh, long long sAb, long long sBh, long long sBb,
    long long sCh, long long sCb, int NB, int gx, int gy) {
    extern __shared__ char lds[];

    // T1 bijective XCD swizzle
    const int nwg = gridDim.x;
    const int q = nwg >> 3, r = nwg & 7;
    const int xcd = blockIdx.x & 7, lid = blockIdx.x >> 3;
    const int wg = (xcd < r ? xcd * (q + 1) : r * (q + 1) + (xcd - r) * q) + lid;
    const int z = wg / (gx * gy);
    const int rem = wg - z * (gx * gy);
    const int by = rem / gx, bx = rem - by * gx;
    const int h = z / NB, bb = z - h * NB;
    A += h * sAh + bb * sAb;
    B += h * sBh + bb * sBb;
    C += h * sCh + bb * sCb;
    const int row0 = by * 256, col0 = bx * 256;

    const int tid  = threadIdx.x;
    const int lane = tid & 63;
    const int wid  = tid >> 6;
    const int wm   = wid >> 2;          // 0..1 -> rows wm*128
    const int wn   = wid & 3;           // 0..3 -> cols wn*64
    const int fr   = lane & 15;
    // 64B rows, swizzle byte ^= ((row>>1)&3)<<4 (R2-verified algebra)
    const int swz  = ((lane >> 4) << 4) ^ (((fr >> 1) & 3) << 4);

    const unsigned ldsbase = (unsigned)(uintptr_t)(char*)lds;
    const unsigned aBase = ldsbase + (unsigned)((wm * 128 + fr) * 64 + swz);
    const unsigned bBase = ldsbase + 32768u + (unsigned)((wn * 64 + fr) * 64 + swz);

    // staging: 512 thr x 16B = 8 KB = half of one 16 KB k-half (rows 0-127);
    // second gload covers rows 128-255. Inverse-swizzled global col.
    const int srow = tid >> 2;                     // 0..127
    const int scol = (((tid & 3) << 4) ^ (((srow >> 1) & 3) << 4)) >> 1;
    const f16* gA = A + (size_t)(row0 + srow) * ldA + scol;
    const f16* gB = B + (size_t)(col0 + srow) * ldB + scol;
    char* lA = (char*)lds + tid * 16;
    char* lB = lA + 32768;

    const int nkt = K >> 6;

#define STG_A(tt, kh, bo) do { \
        const size_t _ko = (size_t)(tt) * 64 + (kh) * 32; \
        gload_lds16(gA + _ko,                     lA + (bo) + (kh) * 16384); \
        gload_lds16(gA + 128 * (size_t)ldA + _ko, lA + (bo) + (kh) * 16384 + 8192); \
    } while (0)
#define STG_B(tt, kh, bo) do { \
        const size_t _ko = (size_t)(tt) * 64 + (kh) * 32; \
        gload_lds16(gB + _ko,                     lB + (bo) + (kh) * 16384); \
        gload_lds16(gB + 128 * (size_t)ldB + _ko, lB + (bo) + (kh) * 16384 + 8192); \
    } while (0)

#define DSR2(r0, r1, addr, o0, o1) \
    asm volatile("ds_read_b128 %0, %2 offset:" #o0 "\n\t" \
                 "ds_read_b128 %1, %2 offset:" #o1 \
                 : "=&v"(r0), "=&v"(r1) : "v"(addr))

#define MF(i, j, av, bv) \
    acc[i][j] = __builtin_amdgcn_mfma_f32_16x16x32_f16(av, bv, acc[i][j], 0, 0, 0)

#define MFMA16(i0) do { \
        __builtin_amdgcn_s_setprio(1); \
        MF(i0+0,0,a0,b0); MF(i0+0,1,a0,b1); MF(i0+0,2,a0,b2); MF(i0+0,3,a0,b3); \
        MF(i0+1,0,a1,b0); MF(i0+1,1,a1,b1); MF(i0+1,2,a1,b2); MF(i0+1,3,a1,b3); \
        MF(i0+2,0,a2,b0); MF(i0+2,1,a2,b1); MF(i0+2,2,a2,b2); MF(i0+2,3,a2,b3); \
        MF(i0+3,0,a3,b0); MF(i0+3,1,a3,b1); MF(i0+3,2,a3,b2); MF(i0+3,3,a3,b3); \
        __builtin_amdgcn_s_setprio(0); \
    } while (0)

    // prologue: T0 all 4 halves + T1 k0 halves (12 loads)
    STG_A(0, 0, 0); STG_B(0, 0, 0);
    STG_A(0, 1, 0); STG_B(0, 1, 0);
    if (nkt > 1) { STG_A(1, 0, 65536); STG_B(1, 0, 65536); }
    VMWAIT8();                        // T0 k0 landed
    __builtin_amdgcn_s_barrier();

    f32x4 acc[8][4] = {};
    f16x8 a0, a1, a2, a3, b0, b1, b2, b3;

    for (int t = 0; t < nkt; ++t) {
        const unsigned bo  = (unsigned)((t & 1) << 16);
        const unsigned bo2 = bo ^ 65536u;
        const unsigned aA = aBase + bo, aB = bBase + bo;

        // ---- ph1: k0, A-frags 0-3 + all B-frags
        if (t + 1 < nkt) STG_A(t + 1, 1, bo2);
        DSR2(a0, a1, aA, 0, 1024);
        DSR2(a2, a3, aA, 2048, 3072);
        DSR2(b0, b1, aB, 0, 1024);
        DSR2(b2, b3, aB, 2048, 3072);
        __builtin_amdgcn_s_barrier();
        LGKM0();
        __builtin_amdgcn_sched_barrier(0);
        MFMA16(0);
        __builtin_amdgcn_s_barrier();

        // ---- ph2: k0, A-frags 4-7 (B held)
        if (t + 1 < nkt) STG_B(t + 1, 1, bo2);
        DSR2(a0, a1, aA, 4096, 5120);
        DSR2(a2, a3, aA, 6144, 7168);
        __builtin_amdgcn_s_barrier();
        LGKM0();
        __builtin_amdgcn_sched_barrier(0);
        MFMA16(4);
        __builtin_amdgcn_s_barrier();
        VMWAIT8();                    // own k1 halves landed

        // ---- ph3: k1, A-frags 0-3 + all B-frags; refill own k0
        if (t + 2 < nkt) STG_A(t + 2, 0, bo);
        DSR2(a0, a1, aA, 16384, 17408);
        DSR2(a2, a3, aA, 18432, 19456);
        DSR2(b0, b1, aB, 16384, 17408);
        DSR2(b2, b3, aB, 18432, 19456);
        __builtin_amdgcn_s_barrier();
        LGKM0();
        __builtin_amdgcn_sched_barrier(0);
        MFMA16(0);
        __builtin_amdgcn_s_barrier();

        // ---- ph4: k1, A-frags 4-7
        if (t + 2 < nkt) STG_B(t + 2, 0, bo);
        DSR2(a0, a1, aA, 20480, 21504);
        DSR2(a2, a3, aA, 22528, 23552);
        __builtin_amdgcn_s_barrier();
        LGKM0();
        __builtin_amdgcn_sched_barrier(0);
        MFMA16(4);
        if (t == nkt - 2) VMWAIT0();  // entering last tile: everything landed
        else              VMWAIT8();  // next tile's k0 landed
        __builtin_amdgcn_s_barrier();
    }
#undef MFMA16
#undef MF
#undef DSR2
#undef STG_A
#undef STG_B

    const int er = (lane >> 4) * 4;
#pragma unroll
    for (int i = 0; i < 8; ++i)
#pragma unroll
        for (int j = 0; j < 4; ++j)
#pragma unroll
            for (int rr = 0; rr < 4; ++rr) {
                size_t idx = (size_t)(row0 + wm * 128 + i * 16 + er + rr) * (size_t)ldC +
                             (size_t)(col0 + wn * 64 + j * 16 + fr);
                C[idx] = (OutT)(acc[i][j][rr] * alpha);
            }
}

// ---------------------------------------------------------------------------
__global__ __launch_bounds__(256) void reduce_split2(const float* __restrict__ p,
                                                     float* __restrict__ o, int n4) {
    int i = blockIdx.x * 256 + threadIdx.x;
    if (i >= n4) return;
    const int b  = i >> 18;
    const int jj = i & 262143;
    const float4* p4 = (const float4*)p;
    const size_t base = (size_t)b * 524288 + jj;
    float4 a = p4[base], c = p4[base + 262144];
    float4 s;
    s.x = a.x + c.x;
    s.y = a.y + c.y;
    s.z = a.z + c.z;
    s.w = a.w + c.w;
    ((float4*)o)[i] = s;
}

// ---------------------------------------------------------------------------
__global__ __launch_bounds__(256) void softmax_rows(f16* __restrict__ P) {
    const size_t row = blockIdx.x;
    f16* p = P + row * 1024;
    const int tid = threadIdx.x, lane = tid & 63, wid = tid >> 6;

    f16x4 v4 = *(const f16x4*)(p + tid * 4);
    float v[4];
#pragma unroll
    for (int t = 0; t < 4; ++t) {
        v[t] = (float)v4[t];
        if (v[t] == 0.0f) v[t] = -9e15f;
    }
    float m = fmaxf(fmaxf(v[0], v[1]), fmaxf(v[2], v[3]));
#pragma unroll
    for (int o = 32; o > 0; o >>= 1) m = fmaxf(m, __shfl_xor(m, o));
    __shared__ float red[8];
    if (lane == 0) red[wid] = m;
    __syncthreads();
    m = fmaxf(fmaxf(red[0], red[1]), fmaxf(red[2], red[3]));

    float e[4], s = 0.f;
#pragma unroll
    for (int t = 0; t < 4; ++t) { e[t] = __expf(v[t] - m); s += e[t]; }
#pragma unroll
    for (int o = 32; o > 0; o >>= 1) s += __shfl_xor(s, o);
    if (lane == 0) red[4 + wid] = s;
    __syncthreads();
    s = red[4] + red[5] + red[6] + red[7];
    float inv = 1.0f / s;

    f16x4 o4;
#pragma unroll
    for (int t = 0; t < 4; ++t) o4[t] = (f16)(e[t] * inv);
    *(f16x4*)(p + tid * 4) = o4;
}

// ---------------------------------------------------------------------------
// Algebra (R6): Mt/G weight products; Aq=q*Mt^T; P=Aq*k^T; Xt=G*v^T;
// out=P*Xt^T (K=8192 split2). 309 GF. Workspace peak 184 MiB.
extern "C" void kernel_launch(void* const* d_in, const int* in_sizes, int n_in,
                              void* d_out, int out_size, void* d_ws, size_t ws_size,
                              hipStream_t stream) {
    const float* q  = (const float*)d_in[0];
    const float* k  = (const float*)d_in[1];
    const float* v  = (const float*)d_in[2];
    const float* Wq = (const float*)d_in[3];
    const float* Wk = (const float*)d_in[4];
    const float* Wv = (const float*)d_in[5];
    const float* Wl = (const float*)d_in[6];
    float* out = (float*)d_out;

    (void)hipFuncSetAttribute((const void*)gemm8p<f16>,
                              hipFuncAttributeMaxDynamicSharedMemorySize, 131072);

    const size_t MB = 1024ull * 1024ull;
    char* ws = (char*)d_ws;
    f16*  q_h  = (f16*)(ws + 0 * MB);
    f16*  k_h  = (f16*)(ws + 8 * MB);
    f16*  v_h  = (f16*)(ws + 16 * MB);
    f16*  Wl_h = (f16*)(ws + 24 * MB);
    f16*  WqT  = (f16*)(ws + 40 * MB);
    f16*  WkT  = (f16*)(ws + 56 * MB);
    f16*  WvT  = (f16*)(ws + 72 * MB);
    f16*  Mt   = (f16*)(ws + 88 * MB);
    f16*  G    = (f16*)(ws + 104 * MB);
    f16*  Aq   = (f16*)(ws + 24 * MB);    // over W bufs (dead after P)
    f16*  P    = (f16*)(ws + 120 * MB);
    f16*  Xt   = (f16*)(ws + 24 * MB);    // over dead Aq
    float* part = (float*)(ws + 88 * MB); // over dead Mt,G

    Cvt4 c4;
    c4.s[0] = q;  c4.d[0] = q_h;  c4.n8[0] = 524288;
    c4.s[1] = k;  c4.d[1] = k_h;  c4.n8[1] = 524288;
    c4.s[2] = v;  c4.d[2] = v_h;  c4.n8[2] = 524288;
    c4.s[3] = Wl; c4.d[3] = Wl_h; c4.n8[3] = 1048576;
    cvt_plain4<<<dim3(4096, 4), 256, 0, stream>>>(c4);

    T3 t3;
    t3.s[0] = Wq; t3.d[0] = WqT;
    t3.s[1] = Wk; t3.d[1] = WkT;
    t3.s[2] = Wv; t3.d[2] = WvT;
    cvt_transpose3<<<6144, 256, 0, stream>>>(t3);

    const long long M1 = 1048576ll;
    const long long M8 = 8388608ll;
    const float SCALE = 0.03125f;
    dim3 blk(256);
    const size_t SMEM = 131072;

    gemm_bt<f16><<<dim3(8, 8, 8), blk, 0, stream>>>(
        WkT, WqT, Mt, 1024, 1024, 1024, 1024, 1.0f,
        M1, 0, M1, 0, M1, 0, 1);
    gemm_bt<f16><<<dim3(8, 8, 8), blk, 0, stream>>>(
        Wl_h, WvT, G, 8192, 1024, 1024, 1024, 1.0f,
        1024, 0, M1, 0, M1, 0, 1);
    gemm8p<f16><<<512, 512, SMEM, stream>>>(
        q_h, Mt, Aq, 1024, 1024, 1024, 1024, 1.0f,
        0, M1, M1, 0, 4 * M1, M1, 4, 4, 4);
    gemm8p<f16><<<512, 512, SMEM, stream>>>(
        Aq, k_h, P, 1024, 1024, 8192, 1024, SCALE,
        4 * M1, M1, 0, M1, 1024, M8, 4, 4, 4);
    gemm8p<f16><<<512, 512, SMEM, stream>>>(
        G, v_h, Xt, 1024, 1024, 8192, 1024, 1.0f,
        M1, 0, 0, M1, 1024, M8, 4, 4, 4);
    softmax_rows<<<32768, 256, 0, stream>>>(P);
    gemm_bt<float><<<dim3(8, 8, 8), blk, 0, stream>>>(
        P, Xt, part, 8192, 8192, 1024, 4096, 1.0f,
        M8, 4096, M8, 4096, 2 * M1, M1, 2);
    reduce_split2<<<4096, 256, 0, stream>>>(part, out, 1048576);
}

// Round 9
// 397.473 us; speedup vs baseline: 1.1335x; 1.1335x over previous
//
#include <hip/hip_runtime.h>
#include <stdint.h>

typedef _Float16 f16;
typedef _Float16 f16x8 __attribute__((ext_vector_type(8)));
typedef _Float16 f16x4 __attribute__((ext_vector_type(4)));
typedef float f32x4 __attribute__((ext_vector_type(4)));

__device__ __forceinline__ void gload_lds16(const void* g, void* l) {
    __builtin_amdgcn_global_load_lds(
        (const __attribute__((address_space(1))) unsigned int*)g,
        (__attribute__((address_space(3))) unsigned int*)l, 16, 0, 0);
}

#define VMWAIT0() asm volatile("s_waitcnt vmcnt(0)" ::: "memory")
#define LGKM0()   asm volatile("s_waitcnt lgkmcnt(0)" ::: "memory")

// ---------------------------------------------------------------------------
// plain f32->f16 conversion, 3 segments: q, k, v
struct Cvt3 {
    const float* s[3];
    f16* d[3];
};
__global__ __launch_bounds__(256) void cvt_plain3(Cvt3 c) {
    const int seg = blockIdx.y;
    const int i = blockIdx.x * 256 + threadIdx.x;   // 524288 chunks of 8
    const float4* s4 = (const float4*)c.s[seg];
    float4 a = s4[2 * (size_t)i];
    float4 b = s4[2 * (size_t)i + 1];
    f16x8 o;
    o[0] = (f16)a.x; o[1] = (f16)a.y; o[2] = (f16)a.z; o[3] = (f16)a.w;
    o[4] = (f16)b.x; o[5] = (f16)b.y; o[6] = (f16)b.z; o[7] = (f16)b.w;
    *(f16x8*)(c.d[seg] + (size_t)i * 8) = o;
}

// ---------------------------------------------------------------------------
// Wl reorder + cvt: Wl[e][h*1024+d] f32 -> Wl_r[h][e][d] f16 (uniform ld=1024)
__global__ __launch_bounds__(256) void cvt_wl(const float* __restrict__ s,
                                              f16* __restrict__ d) {
    const int i = blockIdx.x * 256 + threadIdx.x;   // 1048576 chunks of 8
    const int d8 = i & 127;                         // d-chunk (8 elems)
    const int e  = (i >> 7) & 1023;
    const int h  = i >> 17;
    const float4* s4 = (const float4*)(s + (size_t)e * 8192 + h * 1024 + d8 * 8);
    float4 a = s4[0], b = s4[1];
    f16x8 o;
    o[0] = (f16)a.x; o[1] = (f16)a.y; o[2] = (f16)a.z; o[3] = (f16)a.w;
    o[4] = (f16)b.x; o[5] = (f16)b.y; o[6] = (f16)b.z; o[7] = (f16)b.w;
    *(f16x8*)(d + (size_t)i * 8) = o;
}

// ---------------------------------------------------------------------------
// transpose + cvt: src [h][1024(d)][1024(e)] f32 -> dst [h][1024(e)][1024(d)] f16
struct T3 { const float* s[3]; f16* d[3]; };
__global__ __launch_bounds__(256) void cvt_transpose3(T3 c) {
    const int bid = blockIdx.x;
    const int dt = bid & 15;
    const int et = (bid >> 4) & 15;
    const int zz = bid >> 8;
    const int m = zz >> 3, h = zz & 7;
    const float* src = c.s[m] + (size_t)h * 1048576;
    f16* dst = c.d[m] + (size_t)h * 1048576;
    __shared__ f16 t[64][72];
    const int r  = threadIdx.x >> 2;
    const int cq = threadIdx.x & 3;
    const int d0 = dt * 64, e0 = et * 64;
#pragma unroll
    for (int i = 0; i < 4; ++i) {
        const int cc = cq * 4 + i * 16;
        float4 vv = *(const float4*)(src + (size_t)(d0 + r) * 1024 + e0 + cc);
        t[cc + 0][r] = (f16)vv.x;
        t[cc + 1][r] = (f16)vv.y;
        t[cc + 2][r] = (f16)vv.z;
        t[cc + 3][r] = (f16)vv.w;
    }
    __syncthreads();
#pragma unroll
    for (int i = 0; i < 4; ++i) {
        const int cc = cq * 4 + i * 16;
        f16x4 w;
        w[0] = t[r][cc + 0];
        w[1] = t[r][cc + 1];
        w[2] = t[r][cc + 2];
        w[3] = t[r][cc + 3];
        *(f16x4*)(dst + (size_t)(e0 + r) * 1024 + d0 + cc) = w;
    }
}

// ---------------------------------------------------------------------------
// R1-verified 128x128 BT-GEMM, now 1D grid + T1 bijective XCD swizzle.
// C[m,n] = alpha * sum_k A[m,k]*B[n,k]; wg -> (z, by, bx); z -> (h, b).
template <typename OutT>
__global__ __launch_bounds__(256, 2) void gemm_bt(
    const f16* __restrict__ A, const f16* __restrict__ B, OutT* __restrict__ C,
    int ldA, int ldB, long long ldC, int K, float alpha,
    long long sAh, long long sAb, long long sBh, long long sBb,
    long long sCh, long long sCb, int NB, int gx, int gy) {
    const int nwg = gridDim.x;
    const int q = nwg >> 3, r = nwg & 7;
    const int xcd = blockIdx.x & 7, lid = blockIdx.x >> 3;
    const int wg = (xcd < r ? xcd * (q + 1) : r * (q + 1) + (xcd - r) * q) + lid;
    const int z = wg / (gx * gy);
    const int rem = wg - z * (gx * gy);
    const int by = rem / gx, bx = rem - by * gx;
    const int h = z / NB, bb = z % NB;
    A += h * sAh + bb * sAb;
    B += h * sBh + bb * sBb;
    C += h * sCh + bb * sCb;

    const int row0 = by * 128;
    const int col0 = bx * 128;

    __shared__ __align__(16) f16 smA[128 * 64];
    __shared__ __align__(16) f16 smB[128 * 64];

    const int tid  = threadIdx.x;
    const int lane = tid & 63;
    const int wid  = tid >> 6;
    const int wr   = (wid >> 1) * 64;
    const int wc   = (wid & 1) * 64;
    const int fr   = lane & 15;
    const int fkb  = (lane >> 4) * 16;

    f32x4 acc[4][4] = {};

    const int nkt = K >> 6;
    for (int kt = 0; kt < nkt; ++kt) {
#pragma unroll
        for (int it = 0; it < 4; ++it) {
            int p = (it * 256 + tid) * 16;
            int n = p ^ (((p >> 7) & 7) << 4);
            int rr  = n >> 7;
            int kel = (n & 127) >> 1;
            size_t ga = (size_t)(row0 + rr) * (size_t)ldA + (size_t)(kt * 64 + kel);
            gload_lds16(A + ga, (char*)smA + p);
            size_t gb = (size_t)(col0 + rr) * (size_t)ldB + (size_t)(kt * 64 + kel);
            gload_lds16(B + gb, (char*)smB + p);
        }
        __syncthreads();

#pragma unroll
        for (int ks = 0; ks < 2; ++ks) {
            f16x8 af[4], bf[4];
#pragma unroll
            for (int i = 0; i < 4; ++i) {
                int rowA = wr + i * 16 + fr;
                int na   = rowA * 128 + ks * 64 + fkb;
                af[i] = *(const f16x8*)((const char*)smA + (na ^ ((rowA & 7) << 4)));
                int rowB = wc + i * 16 + fr;
                int nb   = rowB * 128 + ks * 64 + fkb;
                bf[i] = *(const f16x8*)((const char*)smB + (nb ^ ((rowB & 7) << 4)));
            }
#pragma unroll
            for (int i = 0; i < 4; ++i)
#pragma unroll
                for (int j = 0; j < 4; ++j)
                    acc[i][j] = __builtin_amdgcn_mfma_f32_16x16x32_f16(
                        af[i], bf[j], acc[i][j], 0, 0, 0);
        }
        __syncthreads();
    }

    const int er = (lane >> 4) * 4;
#pragma unroll
    for (int i = 0; i < 4; ++i)
#pragma unroll
        for (int j = 0; j < 4; ++j)
#pragma unroll
            for (int rr = 0; rr < 4; ++rr) {
                size_t idx = (size_t)(row0 + wr + i * 16 + er + rr) * (size_t)ldC +
                             (size_t)(col0 + wc + j * 16 + fr);
                C[idx] = (OutT)(acc[i][j][rr] * alpha);
            }
}

// ---------------------------------------------------------------------------
// R4/R7-verified 256x256 BT-GEMM, BK=64, 8 waves, double-buffered LDS,
// 2-phase schedule, T2 swizzle, T5 setprio, T1 bijective XCD swizzle.
template <typename OutT>
__global__ __launch_bounds__(512, 2) void gemm2ph(
    const f16* __restrict__ A, const f16* __restrict__ B, OutT* __restrict__ C,
    int ldA, int ldB, long long ldC, int K, float alpha,
    long long sAh, long long sAb, long long sBh, long long sBb,
    long long sCh, long long sCb, int NB, int gx, int gy) {
    extern __shared__ char lds[];

    const int nwg = gridDim.x;
    const int q = nwg >> 3, r = nwg & 7;
    const int xcd = blockIdx.x & 7, lid = blockIdx.x >> 3;
    const int wg = (xcd < r ? xcd * (q + 1) : r * (q + 1) + (xcd - r) * q) + lid;
    const int z = wg / (gx * gy);
    const int rem = wg - z * (gx * gy);
    const int by = rem / gx, bx = rem - by * gx;
    const int h = z / NB, bb = z - h * NB;
    A += h * sAh + bb * sAb;
    B += h * sBh + bb * sBb;
    C += h * sCh + bb * sCb;
    const int row0 = by * 256, col0 = bx * 256;

    const int tid  = threadIdx.x;
    const int lane = tid & 63;
    const int wid  = tid >> 6;
    const int wm   = wid >> 2;
    const int wn   = wid & 3;
    const int fr   = lane & 15;
    const int fkb  = (lane >> 4) << 4;
    const int sw0  = fkb ^ ((fr & 7) << 4);
    const int sw1  = sw0 ^ 64;

    const unsigned ldsbase = (unsigned)(uintptr_t)(char*)lds;
    const unsigned aRow = ldsbase + (unsigned)((wm * 128 + fr) * 128);
    const unsigned bRow = ldsbase + 32768u + (unsigned)((wn * 64 + fr) * 128);

    const int srow  = tid >> 3;
    const int scol  = (((tid & 7) ^ ((tid >> 3) & 7)) << 4) >> 1;
    const f16* gA = A + (size_t)(row0 + srow) * ldA + scol;
    const f16* gB = B + (size_t)(col0 + srow) * ldB + scol;
    char* lA = (char*)lds + tid * 16;
    char* lB = lA + 32768;

    const int nkt = K >> 6;

#define STAGE(tt, bufo) do { \
        const size_t _ko = (size_t)(tt) * 64; \
        gload_lds16(gA + _ko,                        lA + (bufo)); \
        gload_lds16(gA + 64  * (size_t)ldA + _ko,    lA + (bufo) + 8192); \
        gload_lds16(gA + 128 * (size_t)ldA + _ko,    lA + (bufo) + 16384); \
        gload_lds16(gA + 192 * (size_t)ldA + _ko,    lA + (bufo) + 24576); \
        gload_lds16(gB + _ko,                        lB + (bufo)); \
        gload_lds16(gB + 64  * (size_t)ldB + _ko,    lB + (bufo) + 8192); \
        gload_lds16(gB + 128 * (size_t)ldB + _ko,    lB + (bufo) + 16384); \
        gload_lds16(gB + 192 * (size_t)ldB + _ko,    lB + (bufo) + 24576); \
    } while (0)

#define DSR2(r0, r1, addr, o0, o1) \
    asm volatile("ds_read_b128 %0, %2 offset:" #o0 "\n\t" \
                 "ds_read_b128 %1, %2 offset:" #o1 \
                 : "=&v"(r0), "=&v"(r1) : "v"(addr))

#define MF(i, j, av, bv) \
    acc[i][j] = __builtin_amdgcn_mfma_f32_16x16x32_f16(av, bv, acc[i][j], 0, 0, 0)

#define HALF(sw) do { \
        f16x8 a0, a1, a2, a3, a4, a5, a6, a7, b0, b1, b2, b3; \
        const unsigned aA = aRow + bo + (sw); \
        const unsigned aB = bRow + bo + (sw); \
        DSR2(a0, a1, aA, 0, 2048); \
        DSR2(a2, a3, aA, 4096, 6144); \
        DSR2(a4, a5, aA, 8192, 10240); \
        DSR2(a6, a7, aA, 12288, 14336); \
        DSR2(b0, b1, aB, 0, 2048); \
        DSR2(b2, b3, aB, 4096, 6144); \
        LGKM0(); \
        __builtin_amdgcn_sched_barrier(0); \
        __builtin_amdgcn_s_setprio(1); \
        MF(0,0,a0,b0); MF(0,1,a0,b1); MF(0,2,a0,b2); MF(0,3,a0,b3); \
        MF(1,0,a1,b0); MF(1,1,a1,b1); MF(1,2,a1,b2); MF(1,3,a1,b3); \
        MF(2,0,a2,b0); MF(2,1,a2,b1); MF(2,2,a2,b2); MF(2,3,a2,b3); \
        MF(3,0,a3,b0); MF(3,1,a3,b1); MF(3,2,a3,b2); MF(3,3,a3,b3); \
        MF(4,0,a4,b0); MF(4,1,a4,b1); MF(4,2,a4,b2); MF(4,3,a4,b3); \
        MF(5,0,a5,b0); MF(5,1,a5,b1); MF(5,2,a5,b2); MF(5,3,a5,b3); \
        MF(6,0,a6,b0); MF(6,1,a6,b1); MF(6,2,a6,b2); MF(6,3,a6,b3); \
        MF(7,0,a7,b0); MF(7,1,a7,b1); MF(7,2,a7,b2); MF(7,3,a7,b3); \
        __builtin_amdgcn_s_setprio(0); \
    } while (0)

    STAGE(0, 0);
    VMWAIT0();
    __builtin_amdgcn_s_barrier();

    f32x4 acc[8][4] = {};
    unsigned cur = 0;

    for (int t = 0; t < nkt; ++t) {
        const unsigned bo = cur << 16;
        if (t + 1 < nkt) STAGE(t + 1, bo ^ 65536u);
        HALF(sw0);
        HALF(sw1);
        VMWAIT0();
        __builtin_amdgcn_s_barrier();
        cur ^= 1;
    }
#undef HALF
#undef MF
#undef DSR2
#undef STAGE

    const int er = (lane >> 4) * 4;
#pragma unroll
    for (int i = 0; i < 8; ++i)
#pragma unroll
        for (int j = 0; j < 4; ++j)
#pragma unroll
            for (int rr = 0; rr < 4; ++rr) {
                size_t idx = (size_t)(row0 + wm * 128 + i * 16 + er + rr) * (size_t)ldC +
                             (size_t)(col0 + wn * 64 + j * 16 + fr);
                C[idx] = (OutT)(acc[i][j][rr] * alpha);
            }
}

// ---------------------------------------------------------------------------
__global__ __launch_bounds__(256) void reduce_split2(const float* __restrict__ p,
                                                     float* __restrict__ o, int n4) {
    int i = blockIdx.x * 256 + threadIdx.x;
    if (i >= n4) return;
    const int b  = i >> 18;
    const int jj = i & 262143;
    const float4* p4 = (const float4*)p;
    const size_t base = (size_t)b * 524288 + jj;
    float4 a = p4[base], c = p4[base + 262144];
    float4 s;
    s.x = a.x + c.x;
    s.y = a.y + c.y;
    s.z = a.z + c.z;
    s.w = a.w + c.w;
    ((float4*)o)[i] = s;
}

// ---------------------------------------------------------------------------
__global__ __launch_bounds__(256) void softmax_rows(f16* __restrict__ P) {
    const size_t row = blockIdx.x;
    f16* p = P + row * 1024;
    const int tid = threadIdx.x, lane = tid & 63, wid = tid >> 6;

    f16x4 v4 = *(const f16x4*)(p + tid * 4);
    float v[4];
#pragma unroll
    for (int t = 0; t < 4; ++t) {
        v[t] = (float)v4[t];
        if (v[t] == 0.0f) v[t] = -9e15f;
    }
    float m = fmaxf(fmaxf(v[0], v[1]), fmaxf(v[2], v[3]));
#pragma unroll
    for (int o = 32; o > 0; o >>= 1) m = fmaxf(m, __shfl_xor(m, o));
    __shared__ float red[8];
    if (lane == 0) red[wid] = m;
    __syncthreads();
    m = fmaxf(fmaxf(red[0], red[1]), fmaxf(red[2], red[3]));

    float e[4], s = 0.f;
#pragma unroll
    for (int t = 0; t < 4; ++t) { e[t] = __expf(v[t] - m); s += e[t]; }
#pragma unroll
    for (int o = 32; o > 0; o >>= 1) s += __shfl_xor(s, o);
    if (lane == 0) red[4 + wid] = s;
    __syncthreads();
    s = red[4] + red[5] + red[6] + red[7];
    float inv = 1.0f / s;

    f16x4 o4;
#pragma unroll
    for (int t = 0; t < 4; ++t) o4[t] = (f16)(e[t] * inv);
    *(f16x4*)(p + tid * 4) = o4;
}

// ---------------------------------------------------------------------------
// Algebra (R6): Mt_h = Wk_h^T Wq_h and G_h = Wl_h Wv_h (weight products,
// merged into ONE gemm2ph launch via contiguous [WkT|Wl_r],[WqT|WvT],[Mt|G]);
// Aq = q*Mt^T; P = scale*Aq*k^T; Xt = G*v^T; out = P*Xt^T (K=8192, split2).
// 309 GF. Workspace peak 184 MiB.
extern "C" void kernel_launch(void* const* d_in, const int* in_sizes, int n_in,
                              void* d_out, int out_size, void* d_ws, size_t ws_size,
                              hipStream_t stream) {
    const float* q  = (const float*)d_in[0];
    const float* k  = (const float*)d_in[1];
    const float* v  = (const float*)d_in[2];
    const float* Wq = (const float*)d_in[3];
    const float* Wk = (const float*)d_in[4];
    const float* Wv = (const float*)d_in[5];
    const float* Wl = (const float*)d_in[6];
    float* out = (float*)d_out;

    (void)hipFuncSetAttribute((const void*)gemm2ph<f16>,
                              hipFuncAttributeMaxDynamicSharedMemorySize, 131072);

    const size_t MB = 1024ull * 1024ull;
    char* ws = (char*)d_ws;
    f16*  q_h  = (f16*)(ws + 0 * MB);     // 8 MiB  (dead after Aq)
    f16*  k_h  = (f16*)(ws + 8 * MB);     // 8 MiB  (dead after P)
    f16*  v_h  = (f16*)(ws + 16 * MB);    // 8 MiB  (dead after Xt)
    f16*  WkT  = (f16*)(ws + 24 * MB);    // 16 MiB \ A-region (dead after Mt/G)
    f16*  Wl_r = (f16*)(ws + 40 * MB);    // 16 MiB /
    f16*  WqT  = (f16*)(ws + 56 * MB);    // 16 MiB \ B-region (dead after Mt/G)
    f16*  WvT  = (f16*)(ws + 72 * MB);    // 16 MiB /
    f16*  Mt   = (f16*)(ws + 88 * MB);    // 16 MiB \ C-region
    f16*  G    = (f16*)(ws + 104 * MB);   // 16 MiB /
    f16*  Aq   = (f16*)(ws + 24 * MB);    // 64 MiB over dead W region
    f16*  P    = (f16*)(ws + 120 * MB);   // 64 MiB
    f16*  Xt   = (f16*)(ws + 24 * MB);    // 64 MiB over dead Aq
    float* part = (float*)(ws + 88 * MB); // 32 MiB over dead Mt,G

    Cvt3 c3;
    c3.s[0] = q;  c3.d[0] = q_h;
    c3.s[1] = k;  c3.d[1] = k_h;
    c3.s[2] = v;  c3.d[2] = v_h;
    cvt_plain3<<<dim3(2048, 3), 256, 0, stream>>>(c3);
    cvt_wl<<<4096, 256, 0, stream>>>(Wl, Wl_r);

    T3 t3;
    t3.s[0] = Wq; t3.d[0] = WqT;
    t3.s[1] = Wk; t3.d[1] = WkT;
    t3.s[2] = Wv; t3.d[2] = WvT;
    cvt_transpose3<<<6144, 256, 0, stream>>>(t3);

    const long long M1 = 1048576ll;
    const long long M8 = 8388608ll;
    const float SCALE = 0.03125f;
    const size_t SMEM = 131072;

    // ---- merged weight products: z=0..7 -> Mt_h, z=8..15 -> G_{z-8}
    //      A=[WkT|Wl_r], B=[WqT|WvT], C=[Mt|G], all ld=1024, stride M1
    gemm2ph<f16><<<256, 512, SMEM, stream>>>(
        WkT, WqT, Mt, 1024, 1024, 1024, 1024, 1.0f,
        M1, 0, M1, 0, M1, 0, 1, 4, 4);
    // ---- Aq[h][b] = BT(q_b, Mt_h)
    gemm2ph<f16><<<512, 512, SMEM, stream>>>(
        q_h, Mt, Aq, 1024, 1024, 1024, 1024, 1.0f,
        0, M1, M1, 0, 4 * M1, M1, 4, 4, 4);
    // ---- P[b][s][h*1024+t] = SCALE * BT(Aq[h][b], k_b)
    gemm2ph<f16><<<512, 512, SMEM, stream>>>(
        Aq, k_h, P, 1024, 1024, 8192, 1024, SCALE,
        4 * M1, M1, 0, M1, 1024, M8, 4, 4, 4);
    // ---- Xt[b][e][h*1024+t] = BT(G_h, v_b)
    gemm2ph<f16><<<512, 512, SMEM, stream>>>(
        G, v_h, Xt, 1024, 1024, 8192, 1024, 1.0f,
        M1, 0, 0, M1, 1024, M8, 4, 4, 4);
    // ---- softmax over 32768 contiguous rows of 1024
    softmax_rows<<<32768, 256, 0, stream>>>(P);
    // ---- out partials: split-K=2, z=(b,ks), K=4096 each (128^2 + T1 swizzle)
    gemm_bt<float><<<512, 256, 0, stream>>>(
        P, Xt, part, 8192, 8192, 1024, 4096, 1.0f,
        M8, 4096, M8, 4096, 2 * M1, M1, 2, 8, 8);
    reduce_split2<<<4096, 256, 0, stream>>>(part, out, 1048576);
}